// Round 14
// baseline (182.914 us; speedup 1.0000x reference)
//
#include <hip/hip_runtime.h>
#include <hip/hip_bf16.h>
#include <hip/hip_fp16.h>

typedef _Float16 f16x8 __attribute__((ext_vector_type(8)));
typedef _Float16 f16x4 __attribute__((ext_vector_type(4)));
typedef float    f32x4 __attribute__((ext_vector_type(4)));

#define EPSV 1e-5f

// ---------------- prep: BN fold constants ----------------
__global__ void prep_consts(
    const float* __restrict__ b1, const float* __restrict__ g1, const float* __restrict__ be1,
    const float* __restrict__ m1, const float* __restrict__ v1,
    const float* __restrict__ b2, const float* __restrict__ g2, const float* __restrict__ be2,
    const float* __restrict__ m2, const float* __restrict__ v2,
    const float* __restrict__ b3, const float* __restrict__ g3, const float* __restrict__ be3,
    const float* __restrict__ m3, const float* __restrict__ v3,
    float* __restrict__ sc1, float* __restrict__ sh1,
    float* __restrict__ sc2, float* __restrict__ sh2,
    float* __restrict__ sc3, float* __restrict__ sh3) {
  int t = threadIdx.x;
  if (t < 512) { float s = g1[t] * rsqrtf(v1[t] + EPSV); sc1[t] = s; sh1[t] = be1[t] + (b1[t] - m1[t]) * s; }
  if (t < 256) { float s = g2[t] * rsqrtf(v2[t] + EPSV); sc2[t] = s; sh2[t] = be2[t] + (b2[t] - m2[t]) * s; }
  if (t < 64)  { float s = g3[t] * rsqrtf(v3[t] + EPSV); sc3[t] = s; sh3[t] = be3[t] + (b3[t] - m3[t]) * s; }
}

// ---------------- prep: W2 -> fragment-swizzled f16 (W2T), W3 -> f16 ----------------
// W2T element order: [ks 0..15][cg 0..15][lane 0..63][e 0..7] where
//   ch = cg*16 + (lane&15),  k = ks*32 + (lane>>4)*8 + e.
// A wave's af fragment (mt) load = ONE coalesced 1KB global_load_dwordx4 at
//   W2T + ((ks*16 + chQ*4 + mt)*64 + lane)*8.
__global__ void prep_convert(const float* __restrict__ W2, const float* __restrict__ W3,
                             _Float16* __restrict__ W2T, _Float16* __restrict__ W3h) {
  int tid = blockIdx.x * 256 + threadIdx.x;   // 64 blocks x 256 = 16384
  {
    int lane = tid & 63, cg = (tid >> 6) & 15, ks = tid >> 10;
    int ch = cg * 16 + (lane & 15);
    int k  = ks * 32 + (lane >> 4) * 8;
    const float* src = W2 + (size_t)ch * 512 + k;
    f16x8 v;
    #pragma unroll
    for (int e = 0; e < 8; ++e) v[e] = (_Float16)src[e];
    *(f16x8*)(W2T + (size_t)tid * 8) = v;
  }
  W3h[tid] = (_Float16)W3[tid];   // 64*256 = 16384 elements
}

// ---------------- prep: layer-1 factorization ----------------
// Layout: Ap[b][i][o] (o contiguous, f16). h1 = relu(A'[i] + B'[j]) generated in-kernel.
__global__ void prep_ab(const float* __restrict__ x, const float* __restrict__ W1,
                        const float* __restrict__ sc1, const float* __restrict__ sh1,
                        _Float16* __restrict__ Ap, _Float16* __restrict__ Bp) {
  int b  = blockIdx.x >> 7;
  int og = blockIdx.x & 127;   // group of 4 output channels
  int i  = threadIdx.x;        // point index, coalesced on x
  float accA[4] = {0.f, 0.f, 0.f, 0.f};
  float accB[4] = {0.f, 0.f, 0.f, 0.f};
  const float* xb  = x  + (size_t)b * 128 * 256 + i;
  const float* w1r = W1 + (size_t)og * 4 * 256;   // uniform per block -> s_loads
  for (int c = 0; c < 128; ++c) {
    float xa = xb[c * 256];
    #pragma unroll
    for (int oo = 0; oo < 4; ++oo) {
      accA[oo] = fmaf(w1r[oo * 256 + c],       xa, accA[oo]);
      accB[oo] = fmaf(w1r[oo * 256 + 128 + c], xa, accB[oo]);
    }
  }
  f16x4 oa, ob;
  {
    int o0 = og * 4;
    float4 s = *(const float4*)(sc1 + o0);
    float4 h = *(const float4*)(sh1 + o0);
    oa[0] = (_Float16)(accA[0] * s.x + h.x); oa[1] = (_Float16)(accA[1] * s.y + h.y);
    oa[2] = (_Float16)(accA[2] * s.z + h.z); oa[3] = (_Float16)(accA[3] * s.w + h.w);
    ob[0] = (_Float16)(accB[0] * s.x); ob[1] = (_Float16)(accB[1] * s.y);
    ob[2] = (_Float16)(accB[2] * s.z); ob[3] = (_Float16)(accB[3] * s.w);
  }
  size_t base = ((size_t)(b * 256 + i) << 9) + og * 4;
  *(f16x4*)(Ap + base) = oa;
  *(f16x4*)(Bp + base) = ob;
}

// ---------------- main fused kernel ----------------
// grid: 8192 blocks = b(8) x it(32) x jt(32); block = 256 thr = 4 waves.
// Block tile = 64 points (8i x 8j) x 256 channels; wave w = chQ: 64 ch x 64 pts,
// acc[4][4] = 64 AGPR. af PING-PONG (r12, +12%) kept.
// ROUND 14: 2-stage INTRA-WAVE pipeline. r13 showed 3 blocks/CU is the real
// residency (170-reg/wave budget, only 128 used). Spend the ~40 free regs:
// chunk k+1's LDS reads (bv,av) issue BEFORE chunk k's MFMA cluster, so the
// ~120cy LDS latency hides under the 310cy MFMA stretch; PKGEN ReLU's the av
// registers IN PLACE (av = max(av+bv,0) IS the B-fragment; saves 32 regs).
// ~95 arch + 64 AGPR = ~159 <= 170: still 3 waves/SIMD.
struct alignas(16) Smem {
  union {
    struct { _Float16 sA[8][552]; _Float16 sB[8][552]; } s2;   // 17664 B
    struct { _Float16 h2[64][264]; float part[4][64]; } e;     // 34816 B
  } u;
};  // 34816 B x 3 blocks = 104 KB <= 160 KB

__global__ __launch_bounds__(256, 3) void edge_main(
    const _Float16* __restrict__ Ap, const _Float16* __restrict__ Bp,
    const _Float16* __restrict__ W2T, const _Float16* __restrict__ W3h,
    const float* __restrict__ sc2, const float* __restrict__ sh2,
    const float* __restrict__ sc3, const float* __restrict__ sh3,
    const float* __restrict__ W4, const float* __restrict__ b4,
    float* __restrict__ out) {
  __shared__ Smem sm;
  const int blk = blockIdx.x;
  const int b  = blk >> 10;
  const int it = (blk >> 5) & 31;
  const int jt = blk & 31;
  const int i0 = it * 8, j0 = jt * 8;

  const int t    = threadIdx.x;
  const int w    = t >> 6;      // chQ: channel quarter [64w, +64)
  const int lane = t & 63;
  const int llo  = lane & 15;   // MFMA row/col within fragment
  const int lhi  = lane >> 4;   // MFMA k-group
  const int gj   = llo & 7;     // j-row of this lane's point column
  const int giOff= llo >> 3;    // i-row parity within nt pair

  // ---- stage A'(8 rows) / B'(8 rows) into LDS [row][k] f16, coalesced ----
  if (t < 128) {
    int r = t >> 4, c = (t & 15) * 32;
    const _Float16* src = Ap + ((size_t)(b * 256 + i0 + r) << 9) + c;
    #pragma unroll
    for (int s = 0; s < 4; ++s)
      *(f16x8*)&sm.u.s2.sA[r][c + s * 8] = *(const f16x8*)(src + s * 8);
  } else {
    int tt = t - 128;
    int r = tt >> 4, c = (tt & 15) * 32;
    const _Float16* src = Bp + ((size_t)(b * 256 + j0 + r) << 9) + c;
    #pragma unroll
    for (int s = 0; s < 4; ++s)
      *(f16x8*)&sm.u.s2.sB[r][c + s * 8] = *(const f16x8*)(src + s * 8);
  }

  const f32x4 vzero = {0.f, 0.f, 0.f, 0.f};
  f32x4 acc[4][4];
  #pragma unroll
  for (int mt = 0; mt < 4; ++mt)
    #pragma unroll
    for (int nt = 0; nt < 4; ++nt) acc[mt][nt] = vzero;

  const f16x8 z8 = {};
  // af frag mt of chunk ks lives at: w2base + ks*8192 + mt*512 (f16)
  const _Float16* w2base = W2T + w * 2048 + lane * 8;

#define LOAD_AF(dst, kk)                                                     \
  {                                                                          \
    const _Float16* _p = w2base + (kk) * 8192;                               \
    _Pragma("unroll")                                                        \
    for (int mt = 0; mt < 4; ++mt)                                           \
      dst[mt] = *(const f16x8*)(_p + mt * 512);                              \
  }

// stage 1: LDS reads for chunk kk (latency hides under the next MFMA cluster)
#define LDSRD(avv, bvv, kk)                                                  \
  {                                                                          \
    const int k0 = (kk) * 32 + lhi * 8;                                      \
    bvv = *(const f16x8*)&sm.u.s2.sB[gj][k0];                                \
    _Pragma("unroll")                                                        \
    for (int nt = 0; nt < 4; ++nt)                                           \
      avv[nt] = *(const f16x8*)&sm.u.s2.sA[nt * 2 + giOff][k0];              \
  }

// stage 2: in-place ReLU gen — avv becomes the MFMA B-fragment
#define PKGEN(avv, bvv)                                                      \
  {                                                                          \
    _Pragma("unroll")                                                        \
    for (int nt = 0; nt < 4; ++nt)                                           \
      avv[nt] = __builtin_elementwise_max(avv[nt] + bvv, z8);                \
  }

#define MFMA_C(afv, bfrv)                                                    \
  {                                                                          \
    _Pragma("unroll")                                                        \
    for (int mt = 0; mt < 4; ++mt)                                           \
      _Pragma("unroll")                                                      \
      for (int nt = 0; nt < 4; ++nt)                                         \
        acc[mt][nt] = __builtin_amdgcn_mfma_f32_16x16x32_f16(                \
            afv[mt], bfrv[nt], acc[mt][nt], 0, 0, 0);                        \
  }

  // prologue: af + fragments for chunk 0
  f16x8 afA[4], afB[4];
  f16x8 av0[4], av1[4], bv0, bv1;
  LOAD_AF(afA, 0);

  __syncthreads();   // sA/sB staged; k-loop needs no further barriers

  LDSRD(av0, bv0, 0);
  PKGEN(av0, bv0);

  // ---- layer 2 K-loop: 16 chunks of K=32, barrier-free, 2-stage pipeline ----
  for (int ks = 0; ks < 16; ks += 2) {
    LOAD_AF(afB, ks + 1);          // VMEM for chunk ks+1, in flight across MFMA
    LDSRD(av1, bv1, ks + 1);       // LDS for chunk ks+1, latency under MFMA
    MFMA_C(afA, av0);              // chunk ks
    PKGEN(av1, bv1);               // VALU pipe while matrix pipe drains
    if (ks + 2 < 16) {
      LOAD_AF(afA, ks + 2);
      LDSRD(av0, bv0, ks + 2);
    }
    MFMA_C(afB, av1);              // chunk ks+1
    if (ks + 2 < 16) PKGEN(av0, bv0);
  }
#undef LOAD_AF
#undef LDSRD
#undef PKGEN
#undef MFMA_C

  __syncthreads();   // all waves done with sA/sB; union switches to h2

  // ---- epilogue (single pass): BN2 + ReLU -> h2 (64 pts x this wave's 64 ch) ----
  #pragma unroll
  for (int mt = 0; mt < 4; ++mt) {
    int ch = w * 64 + mt * 16 + lhi * 4;
    float4 s = *(const float4*)(sc2 + ch);
    float4 h = *(const float4*)(sh2 + ch);
    #pragma unroll
    for (int nt = 0; nt < 4; ++nt) {
      int pt = nt * 16 + llo;
      f32x4 a = acc[mt][nt];
      f16x4 hb;
      hb[0] = (_Float16)fmaxf(fmaf(a[0], s.x, h.x), 0.f);
      hb[1] = (_Float16)fmaxf(fmaf(a[1], s.y, h.y), 0.f);
      hb[2] = (_Float16)fmaxf(fmaf(a[2], s.z, h.z), 0.f);
      hb[3] = (_Float16)fmaxf(fmaf(a[3], s.w, h.w), 0.f);
      *(f16x4*)&sm.u.e.h2[pt][ch] = hb;
    }
  }
  __syncthreads();

  // ---- layer 3: wave w -> output channels [16w, 16w+16), all 64 pts ----
  {
    f32x4 acc3[4];
    #pragma unroll
    for (int nt = 0; nt < 4; ++nt) acc3[nt] = vzero;
    const _Float16* w3p = W3h + (size_t)(w * 16 + llo) * 256 + lhi * 8;
    #pragma unroll
    for (int k8 = 0; k8 < 8; ++k8) {
      f16x8 a3 = *(const f16x8*)(w3p + k8 * 32);
      #pragma unroll
      for (int nt = 0; nt < 4; ++nt) {
        f16x8 b3 = *(const f16x8*)&sm.u.e.h2[nt * 16 + llo][k8 * 32 + lhi * 8];
        acc3[nt] = __builtin_amdgcn_mfma_f32_16x16x32_f16(a3, b3, acc3[nt], 0, 0, 0);
      }
    }
    // BN3 + ReLU + W4 fold; reduce over lhi groups via shfl
    int ch3 = w * 16 + lhi * 4;
    float4 s  = *(const float4*)(sc3 + ch3);
    float4 h  = *(const float4*)(sh3 + ch3);
    float4 wv = *(const float4*)(W4 + ch3);
    #pragma unroll
    for (int nt = 0; nt < 4; ++nt) {
      float p = fmaxf(fmaf(acc3[nt][0], s.x, h.x), 0.f) * wv.x
              + fmaxf(fmaf(acc3[nt][1], s.y, h.y), 0.f) * wv.y
              + fmaxf(fmaf(acc3[nt][2], s.z, h.z), 0.f) * wv.z
              + fmaxf(fmaf(acc3[nt][3], s.w, h.w), 0.f) * wv.w;
      p += __shfl_xor(p, 16);
      p += __shfl_xor(p, 32);
      if (lane < 16) sm.u.e.part[w][nt * 16 + llo] = p;   // lhi==0 lanes
    }
  }
  __syncthreads();

  // ---- cross-wave sum + sigmoid + store ----
  if (t < 64) {
    float tot = sm.u.e.part[0][t] + sm.u.e.part[1][t] + sm.u.e.part[2][t]
              + sm.u.e.part[3][t] + b4[0];
    float sg = 1.f / (1.f + __expf(-tot));
    out[(size_t)b * 65536 + (size_t)(i0 + (t >> 3)) * 256 + (j0 + (t & 7))] = sg;
  }
}

// ---------------- launcher ----------------
extern "C" void kernel_launch(void* const* d_in, const int* in_sizes, int n_in,
                              void* d_out, int out_size, void* d_ws, size_t ws_size,
                              hipStream_t stream) {
  const float* x   = (const float*)d_in[0];
  const float* W1  = (const float*)d_in[1];
  const float* b1  = (const float*)d_in[2];
  const float* g1  = (const float*)d_in[3];
  const float* be1 = (const float*)d_in[4];
  const float* m1  = (const float*)d_in[5];
  const float* v1  = (const float*)d_in[6];
  const float* W2  = (const float*)d_in[7];
  const float* b2  = (const float*)d_in[8];
  const float* g2  = (const float*)d_in[9];
  const float* be2 = (const float*)d_in[10];
  const float* m2  = (const float*)d_in[11];
  const float* v2  = (const float*)d_in[12];
  const float* W3  = (const float*)d_in[13];
  const float* b3  = (const float*)d_in[14];
  const float* g3  = (const float*)d_in[15];
  const float* be3 = (const float*)d_in[16];
  const float* m3  = (const float*)d_in[17];
  const float* v3  = (const float*)d_in[18];
  const float* W4  = (const float*)d_in[19];
  const float* b4  = (const float*)d_in[20];

  // workspace layout (~4.6 MB total)
  _Float16* Ap = (_Float16*)d_ws;        // 8*256*512 f16, [b][i][o]
  _Float16* Bp = Ap + 1048576;           // [b][j][o]
  float* sc1 = (float*)(Bp + 1048576);   // 512
  float* sh1 = sc1 + 512;                // 512
  float* sc2 = sh1 + 512;                // 256
  float* sh2 = sc2 + 256;                // 256
  float* sc3 = sh2 + 256;                // 64
  float* sh3 = sc3 + 64;                 // 64
  _Float16* W2T = (_Float16*)(sh3 + 64); // 131072 f16, fragment-swizzled
  _Float16* W3h = W2T + 131072;          // 16384 f16

  prep_consts<<<1, 512, 0, stream>>>(b1, g1, be1, m1, v1, b2, g2, be2, m2, v2,
                                     b3, g3, be3, m3, v3, sc1, sh1, sc2, sh2, sc3, sh3);
  prep_convert<<<64, 256, 0, stream>>>(W2, W3, W2T, W3h);
  prep_ab<<<1024, 256, 0, stream>>>(x, W1, sc1, sh1, Ap, Bp);
  edge_main<<<8192, 256, 0, stream>>>(Ap, Bp, W2T, W3h, sc2, sh2, sc3, sh3, W4, b4, (float*)d_out);
}

// Round 15
// 175.944 us; speedup vs baseline: 1.0396x; 1.0396x over previous
//
#include <hip/hip_runtime.h>
#include <hip/hip_bf16.h>
#include <hip/hip_fp16.h>

typedef _Float16 f16x8 __attribute__((ext_vector_type(8)));
typedef _Float16 f16x4 __attribute__((ext_vector_type(4)));
typedef float    f32x4 __attribute__((ext_vector_type(4)));

#define EPSV 1e-5f

// ---------------- prep: W2 -> fragment-swizzled f16 (W2T), W3 -> f16,
//                  + BN2/BN3 fold constants (block 0) ----------------
// W2T element order: [ks 0..15][cg 0..15][lane 0..63][e 0..7] where
//   ch = cg*16 + (lane&15),  k = ks*32 + (lane>>4)*8 + e.
__global__ void prep_convert(const float* __restrict__ W2, const float* __restrict__ W3,
                             const float* __restrict__ b2, const float* __restrict__ g2,
                             const float* __restrict__ be2, const float* __restrict__ m2,
                             const float* __restrict__ v2,
                             const float* __restrict__ b3, const float* __restrict__ g3,
                             const float* __restrict__ be3, const float* __restrict__ m3,
                             const float* __restrict__ v3,
                             _Float16* __restrict__ W2T, _Float16* __restrict__ W3h,
                             float* __restrict__ sc2, float* __restrict__ sh2,
                             float* __restrict__ sc3, float* __restrict__ sh3) {
  int tid = blockIdx.x * 256 + threadIdx.x;   // 64 blocks x 256 = 16384
  if (blockIdx.x == 0) {
    int t = threadIdx.x;
    if (t < 256) { float s = g2[t] * rsqrtf(v2[t] + EPSV); sc2[t] = s; sh2[t] = be2[t] + (b2[t] - m2[t]) * s; }
    if (t < 64)  { float s = g3[t] * rsqrtf(v3[t] + EPSV); sc3[t] = s; sh3[t] = be3[t] + (b3[t] - m3[t]) * s; }
  }
  {
    int lane = tid & 63, cg = (tid >> 6) & 15, ks = tid >> 10;
    int ch = cg * 16 + (lane & 15);
    int k  = ks * 32 + (lane >> 4) * 8;
    const float* src = W2 + (size_t)ch * 512 + k;
    f16x8 v;
    #pragma unroll
    for (int e = 0; e < 8; ++e) v[e] = (_Float16)src[e];
    *(f16x8*)(W2T + (size_t)tid * 8) = v;
  }
  W3h[tid] = (_Float16)W3[tid];   // 64*256 = 16384 elements
}

// ---------------- prep: layer-1 factorization (BN1 fold inlined) ----------------
// Layout: Ap[b][i][o] (o contiguous, f16). h1 = relu(A'[i] + B'[j]) generated in-kernel.
// ROUND 15: c-loop unrolled x8 (8 loads in flight, 8 independent FMA chains);
// sc1/sh1 computed inline (4 scalar rsqrt per block) -> prep_consts launch deleted.
__global__ void prep_ab(const float* __restrict__ x, const float* __restrict__ W1,
                        const float* __restrict__ b1, const float* __restrict__ g1,
                        const float* __restrict__ be1, const float* __restrict__ m1,
                        const float* __restrict__ v1,
                        _Float16* __restrict__ Ap, _Float16* __restrict__ Bp) {
  int b  = blockIdx.x >> 7;
  int og = blockIdx.x & 127;   // group of 4 output channels
  int i  = threadIdx.x;        // point index, coalesced on x
  float accA[4] = {0.f, 0.f, 0.f, 0.f};
  float accB[4] = {0.f, 0.f, 0.f, 0.f};
  const float* xb  = x  + (size_t)b * 128 * 256 + i;
  const float* w1r = W1 + (size_t)og * 4 * 256;   // uniform per block -> s_loads
  #pragma unroll 8
  for (int c = 0; c < 128; ++c) {
    float xa = xb[c * 256];
    #pragma unroll
    for (int oo = 0; oo < 4; ++oo) {
      accA[oo] = fmaf(w1r[oo * 256 + c],       xa, accA[oo]);
      accB[oo] = fmaf(w1r[oo * 256 + 128 + c], xa, accB[oo]);
    }
  }
  f16x4 oa, ob;
  {
    int o0 = og * 4;
    #pragma unroll
    for (int oo = 0; oo < 4; ++oo) {
      float s = g1[o0 + oo] * rsqrtf(v1[o0 + oo] + EPSV);          // SGPR-uniform
      float h = be1[o0 + oo] + (b1[o0 + oo] - m1[o0 + oo]) * s;
      oa[oo] = (_Float16)(accA[oo] * s + h);
      ob[oo] = (_Float16)(accB[oo] * s);
    }
  }
  size_t base = ((size_t)(b * 256 + i) << 9) + og * 4;
  *(f16x4*)(Ap + base) = oa;
  *(f16x4*)(Bp + base) = ob;
}

// ---------------- main fused kernel (round-12 exact: best verified) ----------------
// grid: 8192 blocks = b(8) x it(32) x jt(32); block = 256 thr = 4 waves.
// Block tile = 64 points (8i x 8j) x 256 channels; wave w = chQ: 64 ch x 64 pts,
// acc[4][4] = 64 AGPR. af PING-PONG double-buffer (r12, verified 174->155).
// r13 (4 blocks/CU): null — HW stays at 3. r14 (intra-wave pipeline): regressed
// — compiler already schedules this loop near-optimally; VGPR must stay 64.
struct alignas(16) Smem {
  union {
    struct { _Float16 sA[8][552]; _Float16 sB[8][552]; } s2;   // 17664 B
    struct { _Float16 h2[64][264]; float part[4][64]; } e;     // 34816 B
  } u;
};  // 34816 B x 3 blocks = 104 KB <= 160 KB

__global__ __launch_bounds__(256, 3) void edge_main(
    const _Float16* __restrict__ Ap, const _Float16* __restrict__ Bp,
    const _Float16* __restrict__ W2T, const _Float16* __restrict__ W3h,
    const float* __restrict__ sc2, const float* __restrict__ sh2,
    const float* __restrict__ sc3, const float* __restrict__ sh3,
    const float* __restrict__ W4, const float* __restrict__ b4,
    float* __restrict__ out) {
  __shared__ Smem sm;
  const int blk = blockIdx.x;
  const int b  = blk >> 10;
  const int it = (blk >> 5) & 31;
  const int jt = blk & 31;
  const int i0 = it * 8, j0 = jt * 8;

  const int t    = threadIdx.x;
  const int w    = t >> 6;      // chQ: channel quarter [64w, +64)
  const int lane = t & 63;
  const int llo  = lane & 15;   // MFMA row/col within fragment
  const int lhi  = lane >> 4;   // MFMA k-group
  const int gj   = llo & 7;     // j-row of this lane's point column
  const int giOff= llo >> 3;    // i-row parity within nt pair

  // ---- stage A'(8 rows) / B'(8 rows) into LDS [row][k] f16, coalesced ----
  if (t < 128) {
    int r = t >> 4, c = (t & 15) * 32;
    const _Float16* src = Ap + ((size_t)(b * 256 + i0 + r) << 9) + c;
    #pragma unroll
    for (int s = 0; s < 4; ++s)
      *(f16x8*)&sm.u.s2.sA[r][c + s * 8] = *(const f16x8*)(src + s * 8);
  } else {
    int tt = t - 128;
    int r = tt >> 4, c = (tt & 15) * 32;
    const _Float16* src = Bp + ((size_t)(b * 256 + j0 + r) << 9) + c;
    #pragma unroll
    for (int s = 0; s < 4; ++s)
      *(f16x8*)&sm.u.s2.sB[r][c + s * 8] = *(const f16x8*)(src + s * 8);
  }

  const f32x4 vzero = {0.f, 0.f, 0.f, 0.f};
  f32x4 acc[4][4];
  #pragma unroll
  for (int mt = 0; mt < 4; ++mt)
    #pragma unroll
    for (int nt = 0; nt < 4; ++nt) acc[mt][nt] = vzero;

  const f16x8 z8 = {};
  // af frag mt of chunk ks lives at: w2base + ks*8192 + mt*512 (f16)
  const _Float16* w2base = W2T + w * 2048 + lane * 8;

#define LOAD_AF(dst, kk)                                                     \
  {                                                                          \
    const _Float16* _p = w2base + (kk) * 8192;                               \
    _Pragma("unroll")                                                        \
    for (int mt = 0; mt < 4; ++mt)                                           \
      dst[mt] = *(const f16x8*)(_p + mt * 512);                              \
  }

#define KSTEP(afv, kk)                                                       \
  {                                                                          \
    const int k0 = (kk) * 32 + lhi * 8;                                      \
    f16x8 bv = *(const f16x8*)&sm.u.s2.sB[gj][k0];                           \
    f16x8 bfr[4];                                                            \
    _Pragma("unroll")                                                        \
    for (int nt = 0; nt < 4; ++nt) {                                         \
      f16x8 av = *(const f16x8*)&sm.u.s2.sA[nt * 2 + giOff][k0];             \
      f16x8 sv = av + bv;                                                    \
      bfr[nt] = __builtin_elementwise_max(sv, z8);                           \
    }                                                                        \
    _Pragma("unroll")                                                        \
    for (int mt = 0; mt < 4; ++mt)                                           \
      _Pragma("unroll")                                                      \
      for (int nt = 0; nt < 4; ++nt)                                         \
        acc[mt][nt] = __builtin_amdgcn_mfma_f32_16x16x32_f16(                \
            afv[mt], bfr[nt], acc[mt][nt], 0, 0, 0);                         \
  }

  // prologue: af for chunk 0 (issues during staging-store latency)
  f16x8 afA[4], afB[4];
  LOAD_AF(afA, 0);

  __syncthreads();   // sA/sB staged; k-loop needs no further barriers

  // ---- layer 2 K-loop: 16 chunks of K=32, barrier-free, af ping-pong ----
  for (int ks = 0; ks < 16; ks += 2) {
    LOAD_AF(afB, ks + 1);          // in flight across KSTEP(afA)
    KSTEP(afA, ks);
    if (ks + 2 < 16) LOAD_AF(afA, ks + 2);
    KSTEP(afB, ks + 1);
  }
#undef LOAD_AF
#undef KSTEP

  __syncthreads();   // all waves done with sA/sB; union switches to h2

  // ---- epilogue (single pass): BN2 + ReLU -> h2 (64 pts x this wave's 64 ch) ----
  #pragma unroll
  for (int mt = 0; mt < 4; ++mt) {
    int ch = w * 64 + mt * 16 + lhi * 4;
    float4 s = *(const float4*)(sc2 + ch);
    float4 h = *(const float4*)(sh2 + ch);
    #pragma unroll
    for (int nt = 0; nt < 4; ++nt) {
      int pt = nt * 16 + llo;
      f32x4 a = acc[mt][nt];
      f16x4 hb;
      hb[0] = (_Float16)fmaxf(fmaf(a[0], s.x, h.x), 0.f);
      hb[1] = (_Float16)fmaxf(fmaf(a[1], s.y, h.y), 0.f);
      hb[2] = (_Float16)fmaxf(fmaf(a[2], s.z, h.z), 0.f);
      hb[3] = (_Float16)fmaxf(fmaf(a[3], s.w, h.w), 0.f);
      *(f16x4*)&sm.u.e.h2[pt][ch] = hb;
    }
  }
  __syncthreads();

  // ---- layer 3: wave w -> output channels [16w, 16w+16), all 64 pts ----
  {
    f32x4 acc3[4];
    #pragma unroll
    for (int nt = 0; nt < 4; ++nt) acc3[nt] = vzero;
    const _Float16* w3p = W3h + (size_t)(w * 16 + llo) * 256 + lhi * 8;
    #pragma unroll
    for (int k8 = 0; k8 < 8; ++k8) {
      f16x8 a3 = *(const f16x8*)(w3p + k8 * 32);
      #pragma unroll
      for (int nt = 0; nt < 4; ++nt) {
        f16x8 b3 = *(const f16x8*)&sm.u.e.h2[nt * 16 + llo][k8 * 32 + lhi * 8];
        acc3[nt] = __builtin_amdgcn_mfma_f32_16x16x32_f16(a3, b3, acc3[nt], 0, 0, 0);
      }
    }
    // BN3 + ReLU + W4 fold; reduce over lhi groups via shfl
    int ch3 = w * 16 + lhi * 4;
    float4 s  = *(const float4*)(sc3 + ch3);
    float4 h  = *(const float4*)(sh3 + ch3);
    float4 wv = *(const float4*)(W4 + ch3);
    #pragma unroll
    for (int nt = 0; nt < 4; ++nt) {
      float p = fmaxf(fmaf(acc3[nt][0], s.x, h.x), 0.f) * wv.x
              + fmaxf(fmaf(acc3[nt][1], s.y, h.y), 0.f) * wv.y
              + fmaxf(fmaf(acc3[nt][2], s.z, h.z), 0.f) * wv.z
              + fmaxf(fmaf(acc3[nt][3], s.w, h.w), 0.f) * wv.w;
      p += __shfl_xor(p, 16);
      p += __shfl_xor(p, 32);
      if (lane < 16) sm.u.e.part[w][nt * 16 + llo] = p;   // lhi==0 lanes
    }
  }
  __syncthreads();

  // ---- cross-wave sum + sigmoid + store ----
  if (t < 64) {
    float tot = sm.u.e.part[0][t] + sm.u.e.part[1][t] + sm.u.e.part[2][t]
              + sm.u.e.part[3][t] + b4[0];
    float sg = 1.f / (1.f + __expf(-tot));
    out[(size_t)b * 65536 + (size_t)(i0 + (t >> 3)) * 256 + (j0 + (t & 7))] = sg;
  }
}

// ---------------- launcher ----------------
extern "C" void kernel_launch(void* const* d_in, const int* in_sizes, int n_in,
                              void* d_out, int out_size, void* d_ws, size_t ws_size,
                              hipStream_t stream) {
  const float* x   = (const float*)d_in[0];
  const float* W1  = (const float*)d_in[1];
  const float* b1  = (const float*)d_in[2];
  const float* g1  = (const float*)d_in[3];
  const float* be1 = (const float*)d_in[4];
  const float* m1  = (const float*)d_in[5];
  const float* v1  = (const float*)d_in[6];
  const float* W2  = (const float*)d_in[7];
  const float* b2  = (const float*)d_in[8];
  const float* g2  = (const float*)d_in[9];
  const float* be2 = (const float*)d_in[10];
  const float* m2  = (const float*)d_in[11];
  const float* v2  = (const float*)d_in[12];
  const float* W3  = (const float*)d_in[13];
  const float* b3  = (const float*)d_in[14];
  const float* g3  = (const float*)d_in[15];
  const float* be3 = (const float*)d_in[16];
  const float* m3  = (const float*)d_in[17];
  const float* v3  = (const float*)d_in[18];
  const float* W4  = (const float*)d_in[19];
  const float* b4  = (const float*)d_in[20];

  // workspace layout (~4.6 MB total)
  _Float16* Ap = (_Float16*)d_ws;        // 8*256*512 f16, [b][i][o]
  _Float16* Bp = Ap + 1048576;           // [b][j][o]
  float* sc2 = (float*)(Bp + 1048576);   // 256
  float* sh2 = sc2 + 256;                // 256
  float* sc3 = sh2 + 256;                // 64
  float* sh3 = sc3 + 64;                 // 64
  _Float16* W2T = (_Float16*)(sh3 + 64); // 131072 f16, fragment-swizzled
  _Float16* W3h = W2T + 131072;          // 16384 f16

  prep_convert<<<64, 256, 0, stream>>>(W2, W3, b2, g2, be2, m2, v2,
                                       b3, g3, be3, m3, v3,
                                       W2T, W3h, sc2, sh2, sc3, sh3);
  prep_ab<<<1024, 256, 0, stream>>>(x, W1, b1, g1, be1, m1, v1, Ap, Bp);
  edge_main<<<8192, 256, 0, stream>>>(Ap, Bp, W2T, W3h, sc2, sh2, sc3, sh3, W4, b4, (float*)d_out);
}